// Round 1
// baseline (454.086 us; speedup 1.0000x reference)
//
#include <hip/hip_runtime.h>
#include <hip/hip_bf16.h>
#include <math.h>

typedef __bf16 bf16;
typedef __bf16 bf16x8 __attribute__((ext_vector_type(8)));
typedef __bf16 bf16x4 __attribute__((ext_vector_type(4)));
typedef float  f32x4  __attribute__((ext_vector_type(4)));

#define MFMA(a, b, c) __builtin_amdgcn_mfma_f32_16x16x32_bf16((a), (b), (c), 0, 0, 0)

// ---------------------------------------------------------------------------
// Kernel A: relative-position-bias MLP.  961 rows of a 2->12->12->12->6 MLP
// with LayerNorm+ReLU between matmuls.  Output pos_out[h][i] (head-major).
// ---------------------------------------------------------------------------
__global__ void pos_mlp_kernel(
    const float* __restrict__ pw0, const float* __restrict__ pb0,
    const float* __restrict__ g1,  const float* __restrict__ be1,
    const float* __restrict__ w1,  const float* __restrict__ b1,
    const float* __restrict__ g2,  const float* __restrict__ be2,
    const float* __restrict__ w2,  const float* __restrict__ b2,
    const float* __restrict__ g3,  const float* __restrict__ be3,
    const float* __restrict__ w3,  const float* __restrict__ b3,
    float* __restrict__ pos_out) {
  int i = blockIdx.x * blockDim.x + threadIdx.x;
  if (i >= 961) return;
  float bh = (float)(i / 31) - 15.0f;   // ph component (ij meshgrid, axis 0)
  float bw = (float)(i % 31) - 15.0f;   // pw component
  float xv[12];
#pragma unroll
  for (int j = 0; j < 12; j++) xv[j] = bh * pw0[j] + bw * pw0[12 + j] + pb0[j];
  const float* G[3]  = {g1, g2, g3};
  const float* BE[3] = {be1, be2, be3};
  const float* W[3]  = {w1, w2, w3};
  const float* BB[3] = {b1, b2, b3};
#pragma unroll
  for (int s = 0; s < 3; s++) {
    float m = 0.f;
#pragma unroll
    for (int j = 0; j < 12; j++) m += xv[j];
    m *= (1.0f / 12.0f);
    float v = 0.f;
#pragma unroll
    for (int j = 0; j < 12; j++) { float d = xv[j] - m; v += d * d; }
    v *= (1.0f / 12.0f);
    float inv = 1.0f / sqrtf(v + 1e-5f);
    float y[12];
#pragma unroll
    for (int j = 0; j < 12; j++) {
      float t = (xv[j] - m) * inv * G[s][j] + BE[s][j];
      y[j] = t > 0.f ? t : 0.f;
    }
    int oc = (s == 2) ? 6 : 12;
    float on[12];
    for (int c = 0; c < oc; c++) {
      float acc = BB[s][c];
#pragma unroll
      for (int j = 0; j < 12; j++) acc += y[j] * W[s][j * oc + c];
      on[c] = acc;
    }
    for (int c = 0; c < 12; c++) xv[c] = (c < oc) ? on[c] : 0.f;
  }
  for (int hh = 0; hh < 6; hh++) pos_out[hh * 961 + i] = xv[hh];
}

// ---------------------------------------------------------------------------
// Kernel B: fused per-(window,head) QKV projection + flash attention.
// grid = 1536 blocks (b,h), 256 threads (4 waves, each owns 64 Q rows).
// LDS layout (bytes):
//   qs  [256][40] bf16 @ 0       (pad 40: 80B stride -> 2-way banks, free)
//   ks  [256][40] bf16 @ 20480
//   vs  [32][264] bf16 @ 40960   (V transposed: [dim][kpos])
//   posh[961] f32     @ 57856
//   bias[96]  f32     @ 61760
//   wt  [96][200] bf16 @ 62208   (W^T slices, phase-2 only)
//   p   [4][64][72] bf16 @ 62208 (per-wave P tiles, phase-3, overlaps wt)
// ---------------------------------------------------------------------------
#define SM_QS   0
#define SM_KS   20480
#define SM_VS   40960
#define SM_POS  57856
#define SM_BIAS 61760
#define SM_WT   62208
#define SMEM_B  100608

__global__ __launch_bounds__(256) void attn_kernel(
    const float* __restrict__ x, const float* __restrict__ mask,
    const float* __restrict__ w_qkv, const float* __restrict__ b_qkv,
    const float* __restrict__ posg, bf16* __restrict__ ctx) {
  extern __shared__ char smem[];
  bf16*  qs    = (bf16*)(smem + SM_QS);
  bf16*  ksm   = (bf16*)(smem + SM_KS);
  bf16*  vsm   = (bf16*)(smem + SM_VS);
  float* posh  = (float*)(smem + SM_POS);
  float* biasl = (float*)(smem + SM_BIAS);
  bf16*  wt    = (bf16*)(smem + SM_WT);

  const int tid = threadIdx.x;
  const int bid = blockIdx.x;
  // swizzle: all 24 blocks sharing mask slice s land on the same XCD
  const int s_ = bid & 63, j_ = bid >> 6;
  const int g_ = j_ & 3, h = j_ >> 2;     // h in 0..5
  const int b = g_ * 64 + s_;

  // ---- stage pos row, bias, W^T slices ----
  for (int i2 = tid; i2 < 961; i2 += 256) posh[i2] = posg[h * 961 + i2];
  for (int i2 = tid; i2 < 96; i2 += 256)
    biasl[i2] = b_qkv[(i2 >> 5) * 192 + h * 32 + (i2 & 31)];
  for (int idx = tid; idx < 96 * 192; idx += 256) {
    int k = idx / 96, c = idx % 96;   // consecutive lanes -> consecutive cols (coalesced)
    wt[c * 200 + k] = (bf16)w_qkv[k * 576 + (c >> 5) * 192 + h * 32 + (c & 31)];
  }
  __syncthreads();

  const int lane = tid & 63, w = tid >> 6;
  const int cI = lane & 15, gI = lane >> 4;
  const float* xb = x + (size_t)b * (256 * 192);

  // ---- phase 2: QKV projection (rows w*64 .. w*64+63) ----
  bf16x8 afr[4][6];
#pragma unroll
  for (int rt = 0; rt < 4; rt++) {
#pragma unroll
    for (int kk = 0; kk < 6; kk++) {
      const float* p = xb + (w * 64 + rt * 16 + cI) * 192 + kk * 32 + gI * 8;
      float4 f0 = *(const float4*)p;
      float4 f1 = *(const float4*)(p + 4);
      bf16x8 a;
      a[0] = (bf16)f0.x; a[1] = (bf16)f0.y; a[2] = (bf16)f0.z; a[3] = (bf16)f0.w;
      a[4] = (bf16)f1.x; a[5] = (bf16)f1.y; a[6] = (bf16)f1.z; a[7] = (bf16)f1.w;
      afr[rt][kk] = a;
    }
  }
#pragma unroll
  for (int mat = 0; mat < 3; mat++) {
#pragma unroll
    for (int ct = 0; ct < 2; ct++) {
      int c = mat * 32 + ct * 16 + cI;
      float bv = biasl[mat * 32 + ct * 16 + cI];
      bf16x8 bfr[6];
#pragma unroll
      for (int kk = 0; kk < 6; kk++)
        bfr[kk] = *(const bf16x8*)(wt + c * 200 + kk * 32 + gI * 8);
#pragma unroll
      for (int rt = 0; rt < 4; rt++) {
        f32x4 acc = {0.f, 0.f, 0.f, 0.f};
#pragma unroll
        for (int kk = 0; kk < 6; kk++) acc = MFMA(afr[rt][kk], bfr[kk], acc);
        int grow0 = w * 64 + rt * 16 + gI * 4;
        int col = ct * 16 + cI;
        if (mat == 0) {
#pragma unroll
          for (int r = 0; r < 4; r++) qs[(grow0 + r) * 40 + col] = (bf16)(acc[r] + bv);
        } else if (mat == 1) {
#pragma unroll
          for (int r = 0; r < 4; r++) ksm[(grow0 + r) * 40 + col] = (bf16)(acc[r] + bv);
        } else {
          bf16x4 v4;
#pragma unroll
          for (int r = 0; r < 4; r++) v4[r] = (bf16)(acc[r] + bv);
          *(bf16x4*)(vsm + col * 264 + grow0) = v4;   // transposed store [dim][kpos]
        }
      }
    }
  }
  __syncthreads();   // qs/ks/vs complete; wt region now reusable as P

  // ---- phase 3: flash attention over 4 KV tiles of 64 ----
  const float scale = 0.17677669529663687f;   // 32^-0.5
  const float* maskb = mask + (size_t)(b & 63) * (256 * 256);
  bf16* pw = (bf16*)(smem + SM_WT + w * 9216);   // per-wave [64][72]

  bf16x8 qfr[4];
#pragma unroll
  for (int rt = 0; rt < 4; rt++)
    qfr[rt] = *(const bf16x8*)(qs + (w * 64 + rt * 16 + cI) * 40 + gI * 8);

  f32x4 o[4][2];
  float mr[4][4], lr[4][4];
#pragma unroll
  for (int rt = 0; rt < 4; rt++) {
    o[rt][0] = (f32x4){0.f, 0.f, 0.f, 0.f};
    o[rt][1] = (f32x4){0.f, 0.f, 0.f, 0.f};
#pragma unroll
    for (int r = 0; r < 4; r++) { mr[rt][r] = -3.0e38f; lr[rt][r] = 0.f; }
  }

  for (int kt = 0; kt < 4; kt++) {
    bf16x8 kfr[4];
#pragma unroll
    for (int ct = 0; ct < 4; ct++)
      kfr[ct] = *(const bf16x8*)(ksm + (kt * 64 + ct * 16 + cI) * 40 + gI * 8);
    f32x4 sa[4][4];
#pragma unroll
    for (int rt = 0; rt < 4; rt++) {
#pragma unroll
      for (int ct = 0; ct < 4; ct++) {
        f32x4 z = {0.f, 0.f, 0.f, 0.f};
        sa[rt][ct] = MFMA(qfr[rt], kfr[ct], z);
      }
    }
#pragma unroll
    for (int rt = 0; rt < 4; rt++) {
      int n0 = w * 64 + rt * 16 + gI * 4;
#pragma unroll
      for (int r = 0; r < 4; r++) {
        int n = n0 + r;
        int rn = n >> 4, cn = n & 15;
#pragma unroll
        for (int ct = 0; ct < 4; ct++) {
          int mm = kt * 64 + ct * 16 + cI;
          int rm = mm >> 4, cm = mm & 15;
          float pv = posh[(rn - rm + 15) * 31 + (cn - cm + 15)];
          float mv = maskb[n * 256 + mm];
          sa[rt][ct][r] = sa[rt][ct][r] * scale + pv + mv;
        }
        float t = fmaxf(fmaxf(sa[rt][0][r], sa[rt][1][r]),
                        fmaxf(sa[rt][2][r], sa[rt][3][r]));
#pragma unroll
        for (int off = 1; off < 16; off <<= 1) t = fmaxf(t, __shfl_xor(t, off));
        float mn = fmaxf(mr[rt][r], t);
        float fsc = __expf(mr[rt][r] - mn);
        mr[rt][r] = mn;
        float sum = 0.f;
#pragma unroll
        for (int ct = 0; ct < 4; ct++) {
          float pp = __expf(sa[rt][ct][r] - mn);
          sa[rt][ct][r] = pp;
          sum += pp;
        }
#pragma unroll
        for (int off = 1; off < 16; off <<= 1) sum += __shfl_xor(sum, off);
        lr[rt][r] = lr[rt][r] * fsc + sum;
        o[rt][0][r] *= fsc;
        o[rt][1][r] *= fsc;
#pragma unroll
        for (int ct = 0; ct < 4; ct++)
          pw[(rt * 16 + gI * 4 + r) * 72 + ct * 16 + cI] = (bf16)sa[rt][ct][r];
      }
    }
    // P writes (this wave only) must land before re-reading as A-frags
    asm volatile("s_waitcnt lgkmcnt(0)" ::: "memory");
#pragma unroll
    for (int kc = 0; kc < 2; kc++) {
      bf16x8 pfr[4], vfr[2];
#pragma unroll
      for (int rt = 0; rt < 4; rt++)
        pfr[rt] = *(const bf16x8*)(pw + (rt * 16 + cI) * 72 + kc * 32 + gI * 8);
#pragma unroll
      for (int c2 = 0; c2 < 2; c2++)
        vfr[c2] = *(const bf16x8*)(vsm + (c2 * 16 + cI) * 264 + kt * 64 + kc * 32 + gI * 8);
#pragma unroll
      for (int rt = 0; rt < 4; rt++) {
#pragma unroll
        for (int c2 = 0; c2 < 2; c2++)
          o[rt][c2] = MFMA(pfr[rt], vfr[c2], o[rt][c2]);
      }
    }
  }
  // ---- epilogue: normalize and write ctx (bf16) ----
#pragma unroll
  for (int rt = 0; rt < 4; rt++) {
#pragma unroll
    for (int c2 = 0; c2 < 2; c2++) {
#pragma unroll
      for (int r = 0; r < 4; r++) {
        int n = w * 64 + rt * 16 + gI * 4 + r;
        float val = o[rt][c2][r] / lr[rt][r];
        ctx[((size_t)b * 256 + n) * 192 + h * 32 + c2 * 16 + cI] = (bf16)val;
      }
    }
  }
}

// ---------------------------------------------------------------------------
// Kernel C: out = ctx @ w_proj + b_proj  (65536x192 @ 192x192, fp32 out)
// 512 blocks x 128 rows, W^T staged in LDS.
// ---------------------------------------------------------------------------
#define SMEM_C (192 * 200 * 2)

__global__ __launch_bounds__(256) void proj_kernel(
    const bf16* __restrict__ ctx, const float* __restrict__ w_proj,
    const float* __restrict__ b_proj, float* __restrict__ out) {
  extern __shared__ char smem[];
  bf16* wt = (bf16*)smem;   // [192][200]
  int tid = threadIdx.x;
  for (int idx = tid; idx < 192 * 192; idx += 256) {
    int k = idx / 192, jj = idx % 192;
    wt[jj * 200 + k] = (bf16)w_proj[idx];
  }
  __syncthreads();
  const int lane = tid & 63, w = tid >> 6;
  const int cI = lane & 15, gI = lane >> 4;
  const int RB = blockIdx.x * 128;
  bf16x8 afr[2][6];
#pragma unroll
  for (int rt = 0; rt < 2; rt++) {
#pragma unroll
    for (int kk = 0; kk < 6; kk++)
      afr[rt][kk] = *(const bf16x8*)(ctx + (size_t)(RB + w * 32 + rt * 16 + cI) * 192 +
                                     kk * 32 + gI * 8);
  }
#pragma unroll
  for (int ct = 0; ct < 12; ct++) {
    bf16x8 bfr[6];
#pragma unroll
    for (int kk = 0; kk < 6; kk++)
      bfr[kk] = *(const bf16x8*)(wt + (ct * 16 + cI) * 200 + kk * 32 + gI * 8);
    float bv = b_proj[ct * 16 + cI];
#pragma unroll
    for (int rt = 0; rt < 2; rt++) {
      f32x4 acc = {0.f, 0.f, 0.f, 0.f};
#pragma unroll
      for (int kk = 0; kk < 6; kk++) acc = MFMA(afr[rt][kk], bfr[kk], acc);
#pragma unroll
      for (int r = 0; r < 4; r++)
        out[(size_t)(RB + w * 32 + rt * 16 + gI * 4 + r) * 192 + ct * 16 + cI] =
            acc[r] + bv;
    }
  }
}

// ---------------------------------------------------------------------------
extern "C" void kernel_launch(void* const* d_in, const int* in_sizes, int n_in,
                              void* d_out, int out_size, void* d_ws, size_t ws_size,
                              hipStream_t stream) {
  (void)in_sizes; (void)n_in; (void)out_size; (void)ws_size;
  const float* x      = (const float*)d_in[0];
  const float* mask   = (const float*)d_in[1];
  const float* w_qkv  = (const float*)d_in[2];
  const float* b_qkv  = (const float*)d_in[3];
  const float* w_proj = (const float*)d_in[4];
  const float* b_proj = (const float*)d_in[5];
  const float* pw0    = (const float*)d_in[6];
  const float* pb0    = (const float*)d_in[7];
  const float* g1     = (const float*)d_in[8];
  const float* be1    = (const float*)d_in[9];
  const float* w1     = (const float*)d_in[10];
  const float* b1     = (const float*)d_in[11];
  const float* g2     = (const float*)d_in[12];
  const float* be2    = (const float*)d_in[13];
  const float* w2     = (const float*)d_in[14];
  const float* b2     = (const float*)d_in[15];
  const float* g3     = (const float*)d_in[16];
  const float* be3    = (const float*)d_in[17];
  const float* w3     = (const float*)d_in[18];
  const float* b3     = (const float*)d_in[19];
  // d_in[20]=H, d_in[21]=W : fixed 16x16 for this problem shape

  float* posw = (float*)d_ws;                       // [6][961] fp32
  bf16*  ctx  = (bf16*)((char*)d_ws + 32768);       // [65536][192] bf16
  float* outp = (float*)d_out;

  // allow >64KB dynamic LDS (no-op if already permitted)
  hipFuncSetAttribute((const void*)attn_kernel,
                      hipFuncAttributeMaxDynamicSharedMemorySize, SMEM_B);
  hipFuncSetAttribute((const void*)proj_kernel,
                      hipFuncAttributeMaxDynamicSharedMemorySize, SMEM_C);

  pos_mlp_kernel<<<dim3(4), dim3(256), 0, stream>>>(
      pw0, pb0, g1, be1, w1, b1, g2, be2, w2, b2, g3, be3, w3, b3, posw);
  attn_kernel<<<dim3(1536), dim3(256), SMEM_B, stream>>>(
      x, mask, w_qkv, b_qkv, posw, ctx);
  proj_kernel<<<dim3(512), dim3(256), SMEM_C, stream>>>(
      ctx, w_proj, b_proj, outp);
}

// Round 2
// 182.970 us; speedup vs baseline: 2.4818x; 2.4818x over previous
//
#include <hip/hip_runtime.h>
#include <hip/hip_bf16.h>
#include <math.h>

typedef __bf16 bf16;
typedef __bf16 bf16x8 __attribute__((ext_vector_type(8)));
typedef float  f32x4  __attribute__((ext_vector_type(4)));

#define MFMA(a, b, c) __builtin_amdgcn_mfma_f32_16x16x32_bf16((a), (b), (c), 0, 0, 0)

// ---------------------------------------------------------------------------
// Kernel A: relative-position-bias MLP.  961 rows of 2->12->12->12->6 with
// LayerNorm+ReLU between matmuls.  Output pos_out[h][i] (head-major).
// ---------------------------------------------------------------------------
__global__ void pos_mlp_kernel(
    const float* __restrict__ pw0, const float* __restrict__ pb0,
    const float* __restrict__ g1,  const float* __restrict__ be1,
    const float* __restrict__ w1,  const float* __restrict__ b1,
    const float* __restrict__ g2,  const float* __restrict__ be2,
    const float* __restrict__ w2,  const float* __restrict__ b2,
    const float* __restrict__ g3,  const float* __restrict__ be3,
    const float* __restrict__ w3,  const float* __restrict__ b3,
    float* __restrict__ pos_out) {
  int i = blockIdx.x * blockDim.x + threadIdx.x;
  if (i >= 961) return;
  float bh = (float)(i / 31) - 15.0f;
  float bw = (float)(i % 31) - 15.0f;
  float xv[12];
#pragma unroll
  for (int j = 0; j < 12; j++) xv[j] = bh * pw0[j] + bw * pw0[12 + j] + pb0[j];
  const float* G[3]  = {g1, g2, g3};
  const float* BE[3] = {be1, be2, be3};
  const float* W[3]  = {w1, w2, w3};
  const float* BB[3] = {b1, b2, b3};
#pragma unroll
  for (int s = 0; s < 3; s++) {
    float m = 0.f;
#pragma unroll
    for (int j = 0; j < 12; j++) m += xv[j];
    m *= (1.0f / 12.0f);
    float v = 0.f;
#pragma unroll
    for (int j = 0; j < 12; j++) { float d = xv[j] - m; v += d * d; }
    v *= (1.0f / 12.0f);
    float inv = 1.0f / sqrtf(v + 1e-5f);
    float y[12];
#pragma unroll
    for (int j = 0; j < 12; j++) {
      float t = (xv[j] - m) * inv * G[s][j] + BE[s][j];
      y[j] = t > 0.f ? t : 0.f;
    }
    int oc = (s == 2) ? 6 : 12;
    float on[12];
    for (int c = 0; c < oc; c++) {
      float acc = BB[s][c];
#pragma unroll
      for (int j = 0; j < 12; j++) acc += y[j] * W[s][j * oc + c];
      on[c] = acc;
    }
    for (int c = 0; c < 12; c++) xv[c] = (c < oc) ? on[c] : 0.f;
  }
  for (int hh = 0; hh < 6; hh++) pos_out[hh * 961 + i] = xv[hh];
}

// ---------------------------------------------------------------------------
// Kernel B: QKV GEMM.  x(65536x192 f32) @ w_qkv(192x576) + b_qkv -> bf16
// scattered to qkv[b][h][mat][n][d]  (d=32).
// grid = (512 row-blocks, 3 mats), 256 thr / 4 waves, tile 128x192.
// ---------------------------------------------------------------------------
#define SMEM_G (192 * 200 * 2)

__global__ __launch_bounds__(256) void qkv_gemm_kernel(
    const float* __restrict__ x, const float* __restrict__ w_qkv,
    const float* __restrict__ b_qkv, bf16* __restrict__ qkv) {
  extern __shared__ char smem[];
  bf16* wt = (bf16*)smem;   // [192 c][200 k]
  const int tid = threadIdx.x;
  const int mat = blockIdx.y;
  for (int idx = tid; idx < 192 * 192; idx += 256) {
    int k = idx / 192, c = idx % 192;
    wt[c * 200 + k] = (bf16)w_qkv[k * 576 + mat * 192 + c];
  }
  __syncthreads();
  const int lane = tid & 63, w = tid >> 6;
  const int cI = lane & 15, gI = lane >> 4;
  const int RB = blockIdx.x * 128;
  bf16x8 afr[2][6];
#pragma unroll
  for (int rt = 0; rt < 2; rt++) {
#pragma unroll
    for (int kk = 0; kk < 6; kk++) {
      const float* p = x + (size_t)(RB + w * 32 + rt * 16 + cI) * 192 + kk * 32 + gI * 8;
      float4 f0 = *(const float4*)p;
      float4 f1 = *(const float4*)(p + 4);
      bf16x8 a;
      a[0] = (bf16)f0.x; a[1] = (bf16)f0.y; a[2] = (bf16)f0.z; a[3] = (bf16)f0.w;
      a[4] = (bf16)f1.x; a[5] = (bf16)f1.y; a[6] = (bf16)f1.z; a[7] = (bf16)f1.w;
      afr[rt][kk] = a;
    }
  }
#pragma unroll
  for (int ct = 0; ct < 12; ct++) {
    int col = ct * 16 + cI;                 // 0..191 within this mat
    float bv = b_qkv[mat * 192 + col];
    bf16x8 bfr[6];
#pragma unroll
    for (int kk = 0; kk < 6; kk++)
      bfr[kk] = *(const bf16x8*)(wt + col * 200 + kk * 32 + gI * 8);
    int h = col >> 5, d = col & 31;
#pragma unroll
    for (int rt = 0; rt < 2; rt++) {
      f32x4 acc = {0.f, 0.f, 0.f, 0.f};
#pragma unroll
      for (int kk = 0; kk < 6; kk++) acc = MFMA(afr[rt][kk], bfr[kk], acc);
#pragma unroll
      for (int r = 0; r < 4; r++) {
        int grow = RB + w * 32 + rt * 16 + gI * 4 + r;
        int b = grow >> 8, n = grow & 255;
        qkv[(size_t)((((b * 6 + h) * 3 + mat) << 8) + n) * 32 + d] = (bf16)(acc[r] + bv);
      }
    }
  }
}

// ---------------------------------------------------------------------------
// Kernel C: flash attention per (b, h, half).  grid = 3072, 256 thr / 4 waves,
// each wave owns 32 Q rows.  Q/K direct global->frag; V^T + pos + P in LDS.
// LDS: vs [32][264] bf16 @0 (16896B) | posh [961] f32 @16896 (3844B->pad 3856)
//      pw  4 x [32][72] bf16 @20752  (4608B each)   total 39184 B
// ---------------------------------------------------------------------------
#define SM_VS2   0
#define SM_POS2  16896
#define SM_PW2   20752
#define SMEM_A   39184

__global__ __launch_bounds__(256, 4) void attn_kernel(
    const bf16* __restrict__ qkv, const float* __restrict__ mask,
    const float* __restrict__ posg, bf16* __restrict__ ctx) {
  extern __shared__ char smem[];
  bf16*  vs   = (bf16*)(smem + SM_VS2);
  float* posh = (float*)(smem + SM_POS2);

  const int tid = threadIdx.x;
  const int bid = blockIdx.x;
  const int s_ = bid & 63, j_ = bid >> 6;          // s = mask slice; XCD = s%8
  const int g_ = j_ & 3, t2 = j_ >> 2;
  const int h = t2 % 6, half = t2 / 6;
  const int b = g_ * 64 + s_;

  const bf16* qb = qkv + (size_t)((b * 6 + h) * 3 + 0) * 8192;
  const bf16* kb = qkv + (size_t)((b * 6 + h) * 3 + 1) * 8192;
  const bf16* vb = qkv + (size_t)((b * 6 + h) * 3 + 2) * 8192;

  // ---- stage pos row + V^T ----
  for (int i2 = tid; i2 < 961; i2 += 256) posh[i2] = posg[h * 961 + i2];
  {
    int n = tid;   // one V row per thread
#pragma unroll
    for (int j = 0; j < 4; j++) {
      bf16x8 v8 = *(const bf16x8*)(vb + n * 32 + j * 8);
#pragma unroll
      for (int e = 0; e < 8; e++) vs[(j * 8 + e) * 264 + n] = v8[e];
    }
  }
  __syncthreads();

  const int lane = tid & 63, w = tid >> 6;
  const int cI = lane & 15, gI = lane >> 4;
  const int qrow0 = half * 128 + w * 32;
  bf16* pw = (bf16*)(smem + SM_PW2 + w * 4608);    // per-wave [32][72]

  bf16x8 qfr[2];
#pragma unroll
  for (int rt = 0; rt < 2; rt++)
    qfr[rt] = *(const bf16x8*)(qb + (qrow0 + rt * 16 + cI) * 32 + gI * 8);

  const float scale = 0.17677669529663687f;        // 32^-0.5
  const float* maskb = mask + (size_t)s_ * (256 * 256);

  f32x4 o[2][2];
  float mr[2][4], lr[2][4];
#pragma unroll
  for (int rt = 0; rt < 2; rt++) {
    o[rt][0] = (f32x4){0.f, 0.f, 0.f, 0.f};
    o[rt][1] = (f32x4){0.f, 0.f, 0.f, 0.f};
#pragma unroll
    for (int r = 0; r < 4; r++) { mr[rt][r] = -3.0e38f; lr[rt][r] = 0.f; }
  }

  for (int kt = 0; kt < 4; kt++) {
    bf16x8 kfr[4];
#pragma unroll
    for (int ct = 0; ct < 4; ct++)
      kfr[ct] = *(const bf16x8*)(kb + (kt * 64 + ct * 16 + cI) * 32 + gI * 8);
    f32x4 sa[2][4];
#pragma unroll
    for (int rt = 0; rt < 2; rt++) {
#pragma unroll
      for (int ct = 0; ct < 4; ct++) {
        f32x4 z = {0.f, 0.f, 0.f, 0.f};
        sa[rt][ct] = MFMA(qfr[rt], kfr[ct], z);
      }
    }
#pragma unroll
    for (int rt = 0; rt < 2; rt++) {
#pragma unroll
      for (int r = 0; r < 4; r++) {
        int n = qrow0 + rt * 16 + gI * 4 + r;
        int rn = n >> 4, cn = n & 15;
        const float* mrow = maskb + n * 256 + kt * 64;
#pragma unroll
        for (int ct = 0; ct < 4; ct++) {
          int mm = ct * 16 + cI;               // within kt tile; cm = cI
          int rm = (kt * 64 + mm) >> 4;
          float pv = posh[(rn - rm + 15) * 31 + (cn - cI + 15)];
          float mv = mrow[mm];
          sa[rt][ct][r] = sa[rt][ct][r] * scale + pv + mv;
        }
        float t = fmaxf(fmaxf(sa[rt][0][r], sa[rt][1][r]),
                        fmaxf(sa[rt][2][r], sa[rt][3][r]));
#pragma unroll
        for (int off = 1; off < 16; off <<= 1) t = fmaxf(t, __shfl_xor(t, off));
        float mn = fmaxf(mr[rt][r], t);
        float fsc = __expf(mr[rt][r] - mn);
        mr[rt][r] = mn;
        float sum = 0.f;
#pragma unroll
        for (int ct = 0; ct < 4; ct++) {
          float pp = __expf(sa[rt][ct][r] - mn);
          sa[rt][ct][r] = pp;
          sum += pp;
        }
#pragma unroll
        for (int off = 1; off < 16; off <<= 1) sum += __shfl_xor(sum, off);
        lr[rt][r] = lr[rt][r] * fsc + sum;
        o[rt][0][r] *= fsc;
        o[rt][1][r] *= fsc;
#pragma unroll
        for (int ct = 0; ct < 4; ct++)
          pw[(rt * 16 + gI * 4 + r) * 72 + ct * 16 + cI] = (bf16)sa[rt][ct][r];
      }
    }
    // this wave's P writes must land before re-reading as A-frags
    asm volatile("s_waitcnt lgkmcnt(0)" ::: "memory");
    __builtin_amdgcn_sched_barrier(0);
#pragma unroll
    for (int kc = 0; kc < 2; kc++) {
      bf16x8 pfr[2], vfr[2];
#pragma unroll
      for (int rt = 0; rt < 2; rt++)
        pfr[rt] = *(const bf16x8*)(pw + (rt * 16 + cI) * 72 + kc * 32 + gI * 8);
#pragma unroll
      for (int c2 = 0; c2 < 2; c2++)
        vfr[c2] = *(const bf16x8*)(vs + (c2 * 16 + cI) * 264 + kt * 64 + kc * 32 + gI * 8);
#pragma unroll
      for (int rt = 0; rt < 2; rt++) {
#pragma unroll
        for (int c2 = 0; c2 < 2; c2++)
          o[rt][c2] = MFMA(pfr[rt], vfr[c2], o[rt][c2]);
      }
    }
  }
  // ---- epilogue ----
#pragma unroll
  for (int rt = 0; rt < 2; rt++) {
#pragma unroll
    for (int c2 = 0; c2 < 2; c2++) {
#pragma unroll
      for (int r = 0; r < 4; r++) {
        int n = qrow0 + rt * 16 + gI * 4 + r;
        float val = o[rt][c2][r] / lr[rt][r];
        ctx[((size_t)(b << 8) + n) * 192 + h * 32 + c2 * 16 + cI] = (bf16)val;
      }
    }
  }
}

// ---------------------------------------------------------------------------
// Kernel D: out = ctx @ w_proj + b_proj  (65536x192 @ 192x192, fp32 out)
// ---------------------------------------------------------------------------
#define SMEM_C (192 * 200 * 2)

__global__ __launch_bounds__(256) void proj_kernel(
    const bf16* __restrict__ ctx, const float* __restrict__ w_proj,
    const float* __restrict__ b_proj, float* __restrict__ out) {
  extern __shared__ char smem[];
  bf16* wt = (bf16*)smem;   // [192][200]
  int tid = threadIdx.x;
  for (int idx = tid; idx < 192 * 192; idx += 256) {
    int k = idx / 192, jj = idx % 192;
    wt[jj * 200 + k] = (bf16)w_proj[idx];
  }
  __syncthreads();
  const int lane = tid & 63, w = tid >> 6;
  const int cI = lane & 15, gI = lane >> 4;
  const int RB = blockIdx.x * 128;
  bf16x8 afr[2][6];
#pragma unroll
  for (int rt = 0; rt < 2; rt++) {
#pragma unroll
    for (int kk = 0; kk < 6; kk++)
      afr[rt][kk] = *(const bf16x8*)(ctx + (size_t)(RB + w * 32 + rt * 16 + cI) * 192 +
                                     kk * 32 + gI * 8);
  }
#pragma unroll
  for (int ct = 0; ct < 12; ct++) {
    bf16x8 bfr[6];
#pragma unroll
    for (int kk = 0; kk < 6; kk++)
      bfr[kk] = *(const bf16x8*)(wt + (ct * 16 + cI) * 200 + kk * 32 + gI * 8);
    float bv = b_proj[ct * 16 + cI];
#pragma unroll
    for (int rt = 0; rt < 2; rt++) {
      f32x4 acc = {0.f, 0.f, 0.f, 0.f};
#pragma unroll
      for (int kk = 0; kk < 6; kk++) acc = MFMA(afr[rt][kk], bfr[kk], acc);
#pragma unroll
      for (int r = 0; r < 4; r++)
        out[(size_t)(RB + w * 32 + rt * 16 + gI * 4 + r) * 192 + ct * 16 + cI] =
            acc[r] + bv;
    }
  }
}

// ---------------------------------------------------------------------------
extern "C" void kernel_launch(void* const* d_in, const int* in_sizes, int n_in,
                              void* d_out, int out_size, void* d_ws, size_t ws_size,
                              hipStream_t stream) {
  (void)in_sizes; (void)n_in; (void)out_size; (void)ws_size;
  const float* x      = (const float*)d_in[0];
  const float* mask   = (const float*)d_in[1];
  const float* w_qkv  = (const float*)d_in[2];
  const float* b_qkv  = (const float*)d_in[3];
  const float* w_proj = (const float*)d_in[4];
  const float* b_proj = (const float*)d_in[5];
  const float* pw0    = (const float*)d_in[6];
  const float* pb0    = (const float*)d_in[7];
  const float* g1     = (const float*)d_in[8];
  const float* be1    = (const float*)d_in[9];
  const float* w1     = (const float*)d_in[10];
  const float* b1     = (const float*)d_in[11];
  const float* g2     = (const float*)d_in[12];
  const float* be2    = (const float*)d_in[13];
  const float* w2     = (const float*)d_in[14];
  const float* b2     = (const float*)d_in[15];
  const float* g3     = (const float*)d_in[16];
  const float* be3    = (const float*)d_in[17];
  const float* w3     = (const float*)d_in[18];
  const float* b3     = (const float*)d_in[19];

  float* posw = (float*)d_ws;                                   // 6*961 f32
  bf16*  qkvw = (bf16*)((char*)d_ws + 32768);                   // 75.5 MB
  bf16*  ctx  = (bf16*)((char*)d_ws + 32768 + 75497472);        // 25.2 MB
  float* outp = (float*)d_out;

  hipFuncSetAttribute((const void*)qkv_gemm_kernel,
                      hipFuncAttributeMaxDynamicSharedMemorySize, SMEM_G);
  hipFuncSetAttribute((const void*)proj_kernel,
                      hipFuncAttributeMaxDynamicSharedMemorySize, SMEM_C);

  pos_mlp_kernel<<<dim3(4), dim3(256), 0, stream>>>(
      pw0, pb0, g1, be1, w1, b1, g2, be2, w2, b2, g3, be3, w3, b3, posw);
  qkv_gemm_kernel<<<dim3(512, 3), dim3(256), SMEM_G, stream>>>(
      x, w_qkv, b_qkv, qkvw);
  attn_kernel<<<dim3(3072), dim3(256), SMEM_A, stream>>>(
      qkvw, mask, posw, ctx);
  proj_kernel<<<dim3(512), dim3(256), SMEM_C, stream>>>(
      ctx, w_proj, b_proj, outp);
}

// Round 3
// 169.142 us; speedup vs baseline: 2.6846x; 1.0818x over previous
//
#include <hip/hip_runtime.h>
#include <hip/hip_bf16.h>
#include <math.h>

typedef __bf16 bf16;
typedef __bf16 bf16x8 __attribute__((ext_vector_type(8)));
typedef __bf16 bf16x4 __attribute__((ext_vector_type(4)));
typedef float  f32x4  __attribute__((ext_vector_type(4)));

#define MFMA(a, b, c) __builtin_amdgcn_mfma_f32_16x16x32_bf16((a), (b), (c), 0, 0, 0)

// ---------------------------------------------------------------------------
// Kernel 0: precast w_qkv (f32 [192][576]) -> wqT (bf16 [576 c][192 k])
// ---------------------------------------------------------------------------
__global__ void precast_kernel(const float* __restrict__ w_qkv,
                               bf16* __restrict__ wqT) {
  int idx = blockIdx.x * 256 + threadIdx.x;
  if (idx >= 576 * 192) return;
  int c = idx / 192, k = idx % 192;
  wqT[idx] = (bf16)w_qkv[k * 576 + c];
}

// ---------------------------------------------------------------------------
// Kernel A: relative-position-bias MLP (961 rows, 2->12->12->12->6).
// Output pos_out[h][i] (head-major).
// ---------------------------------------------------------------------------
__global__ void pos_mlp_kernel(
    const float* __restrict__ pw0, const float* __restrict__ pb0,
    const float* __restrict__ g1,  const float* __restrict__ be1,
    const float* __restrict__ w1,  const float* __restrict__ b1,
    const float* __restrict__ g2,  const float* __restrict__ be2,
    const float* __restrict__ w2,  const float* __restrict__ b2,
    const float* __restrict__ g3,  const float* __restrict__ be3,
    const float* __restrict__ w3,  const float* __restrict__ b3,
    float* __restrict__ pos_out) {
  int i = blockIdx.x * blockDim.x + threadIdx.x;
  if (i >= 961) return;
  float bh = (float)(i / 31) - 15.0f;
  float bw = (float)(i % 31) - 15.0f;
  float xv[12];
#pragma unroll
  for (int j = 0; j < 12; j++) xv[j] = bh * pw0[j] + bw * pw0[12 + j] + pb0[j];
  const float* G[3]  = {g1, g2, g3};
  const float* BE[3] = {be1, be2, be3};
  const float* W[3]  = {w1, w2, w3};
  const float* BB[3] = {b1, b2, b3};
#pragma unroll
  for (int s = 0; s < 3; s++) {
    float m = 0.f;
#pragma unroll
    for (int j = 0; j < 12; j++) m += xv[j];
    m *= (1.0f / 12.0f);
    float v = 0.f;
#pragma unroll
    for (int j = 0; j < 12; j++) { float d = xv[j] - m; v += d * d; }
    v *= (1.0f / 12.0f);
    float inv = 1.0f / sqrtf(v + 1e-5f);
    float y[12];
#pragma unroll
    for (int j = 0; j < 12; j++) {
      float t = (xv[j] - m) * inv * G[s][j] + BE[s][j];
      y[j] = t > 0.f ? t : 0.f;
    }
    int oc = (s == 2) ? 6 : 12;
    float on[12];
    for (int c = 0; c < oc; c++) {
      float acc = BB[s][c];
#pragma unroll
      for (int j = 0; j < 12; j++) acc += y[j] * W[s][j * oc + c];
      on[c] = acc;
    }
    for (int c = 0; c < 12; c++) xv[c] = (c < oc) ? on[c] : 0.f;
  }
  for (int hh = 0; hh < 6; hh++) pos_out[hh * 961 + i] = xv[hh];
}

// ---------------------------------------------------------------------------
// Kernel B: QKV GEMM, zero LDS.  x(65536x192 f32) @ wqT(bf16,L2) + b_qkv.
// grid = 512, 256 thr / 4 waves, 32 rows/wave, all 3 mats per block
// (x read exactly once).  Q,K via swapped MFMA -> bf16x4 stores to [n][d];
// V via normal MFMA -> bf16x4 stores to transposed vT[d][n].
// ---------------------------------------------------------------------------
__global__ __launch_bounds__(256) void qkv_gemm_kernel(
    const float* __restrict__ x, const bf16* __restrict__ wqT,
    const float* __restrict__ b_qkv, bf16* __restrict__ qw,
    bf16* __restrict__ kw, bf16* __restrict__ vwT) {
  const int tid = threadIdx.x;
  const int lane = tid & 63, w = tid >> 6;
  const int cI = lane & 15, gI = lane >> 4;
  const int row0 = blockIdx.x * 128 + w * 32;

  // A-fragments: 32 rows of x, f32 -> bf16 (held for all 3 mats)
  bf16x8 afr[2][6];
#pragma unroll
  for (int rt = 0; rt < 2; rt++) {
#pragma unroll
    for (int kk = 0; kk < 6; kk++) {
      const float* p = x + (size_t)(row0 + rt * 16 + cI) * 192 + kk * 32 + gI * 8;
      float4 f0 = *(const float4*)p;
      float4 f1 = *(const float4*)(p + 4);
      bf16x8 a;
      a[0] = (bf16)f0.x; a[1] = (bf16)f0.y; a[2] = (bf16)f0.z; a[3] = (bf16)f0.w;
      a[4] = (bf16)f1.x; a[5] = (bf16)f1.y; a[6] = (bf16)f1.z; a[7] = (bf16)f1.w;
      afr[rt][kk] = a;
    }
  }

#pragma unroll
  for (int mat = 0; mat < 3; mat++) {
#pragma unroll
    for (int ct = 0; ct < 12; ct++) {
      bf16x8 wfr[6];
#pragma unroll
      for (int kk = 0; kk < 6; kk++)
        wfr[kk] = *(const bf16x8*)(wqT + (size_t)(mat * 192 + ct * 16 + cI) * 192 +
                                   kk * 32 + gI * 8);
      if (mat < 2) {
        // swapped: C^T[c][n]; lane col=cI->n, rows gI*4+r -> c (4 consecutive d)
        f32x4 bv4 = *(const f32x4*)(b_qkv + mat * 192 + ct * 16 + gI * 4);
        bf16* dst = (mat == 0) ? qw : kw;
#pragma unroll
        for (int rt = 0; rt < 2; rt++) {
          f32x4 acc = {0.f, 0.f, 0.f, 0.f};
#pragma unroll
          for (int kk = 0; kk < 6; kk++) acc = MFMA(wfr[kk], afr[rt][kk], acc);
          int grow = row0 + rt * 16 + cI;
          int b = grow >> 8, n = grow & 255;
          int c0 = ct * 16 + gI * 4;
          int h = c0 >> 5, d0 = c0 & 31;
          bf16x4 o4;
#pragma unroll
          for (int r = 0; r < 4; r++) o4[r] = (bf16)(acc[r] + bv4[r]);
          *(bf16x4*)(dst + ((size_t)(b * 6 + h) * 256 + n) * 32 + d0) = o4;
        }
      } else {
        // normal: C[n][c]; lane col=cI->c(d), rows -> n (4 consecutive)
        float bv = b_qkv[384 + ct * 16 + cI];
        int c = ct * 16 + cI, h = c >> 5, d = c & 31;
#pragma unroll
        for (int rt = 0; rt < 2; rt++) {
          f32x4 acc = {0.f, 0.f, 0.f, 0.f};
#pragma unroll
          for (int kk = 0; kk < 6; kk++) acc = MFMA(afr[rt][kk], wfr[kk], acc);
          int n0 = row0 + rt * 16 + gI * 4;
          int b = n0 >> 8, n = n0 & 255;
          bf16x4 o4;
#pragma unroll
          for (int r = 0; r < 4; r++) o4[r] = (bf16)(acc[r] + bv);
          *(bf16x4*)(vwT + ((size_t)(b * 6 + h) * 32 + d) * 256 + n) = o4;
        }
      }
    }
  }
}

// ---------------------------------------------------------------------------
// Kernel C: flash attention per (b, h, half).  grid 3072, 4 waves x 32 Q rows.
// Q/K/V^T direct global->frag; only pos + per-wave P in LDS (22.3 KB).
// ---------------------------------------------------------------------------
#define SM_POS2  0
#define SM_PW2   3904
#define SMEM_A   22336

__global__ __launch_bounds__(256, 4) void attn_kernel(
    const bf16* __restrict__ qw, const bf16* __restrict__ kw,
    const bf16* __restrict__ vwT, const float* __restrict__ mask,
    const float* __restrict__ posg, bf16* __restrict__ ctx) {
  extern __shared__ char smem[];
  float* posh = (float*)(smem + SM_POS2);

  const int tid = threadIdx.x;
  const int bid = blockIdx.x;
  const int s_ = bid & 63, j_ = bid >> 6;          // s = mask slice; XCD = s%8
  const int g_ = j_ & 3, t2 = j_ >> 2;
  const int h = t2 % 6, half = t2 / 6;
  const int b = g_ * 64 + s_;

  const bf16* qb = qw  + (size_t)(b * 6 + h) * 8192;
  const bf16* kb = kw  + (size_t)(b * 6 + h) * 8192;
  const bf16* vb = vwT + (size_t)(b * 6 + h) * 8192;

  for (int i2 = tid; i2 < 961; i2 += 256) posh[i2] = posg[h * 961 + i2];
  __syncthreads();

  const int lane = tid & 63, w = tid >> 6;
  const int cI = lane & 15, gI = lane >> 4;
  const int qrow0 = half * 128 + w * 32;
  bf16* pw = (bf16*)(smem + SM_PW2 + w * 4608);    // per-wave [32][72]

  bf16x8 qfr[2];
#pragma unroll
  for (int rt = 0; rt < 2; rt++)
    qfr[rt] = *(const bf16x8*)(qb + (qrow0 + rt * 16 + cI) * 32 + gI * 8);

  const float scale = 0.17677669529663687f;        // 32^-0.5
  const float* maskb = mask + (size_t)s_ * (256 * 256);

  f32x4 o[2][2];
  float mr[2][4], lr[2][4];
#pragma unroll
  for (int rt = 0; rt < 2; rt++) {
    o[rt][0] = (f32x4){0.f, 0.f, 0.f, 0.f};
    o[rt][1] = (f32x4){0.f, 0.f, 0.f, 0.f};
#pragma unroll
    for (int r = 0; r < 4; r++) { mr[rt][r] = -3.0e38f; lr[rt][r] = 0.f; }
  }

  for (int kt = 0; kt < 4; kt++) {
    bf16x8 kfr[4];
#pragma unroll
    for (int ct = 0; ct < 4; ct++)
      kfr[ct] = *(const bf16x8*)(kb + (kt * 64 + ct * 16 + cI) * 32 + gI * 8);
    f32x4 sa[2][4];
#pragma unroll
    for (int rt = 0; rt < 2; rt++) {
#pragma unroll
      for (int ct = 0; ct < 4; ct++) {
        f32x4 z = {0.f, 0.f, 0.f, 0.f};
        sa[rt][ct] = MFMA(qfr[rt], kfr[ct], z);
      }
    }
#pragma unroll
    for (int rt = 0; rt < 2; rt++) {
#pragma unroll
      for (int r = 0; r < 4; r++) {
        int n = qrow0 + rt * 16 + gI * 4 + r;
        int rn = n >> 4, cn = n & 15;
        const float* mrow = maskb + n * 256 + kt * 64;
#pragma unroll
        for (int ct = 0; ct < 4; ct++) {
          int rm = kt * 4 + ct;                    // (kt*64+ct*16+cI)>>4
          float pv = posh[(rn - rm + 15) * 31 + (cn - cI + 15)];
          float mv = mrow[ct * 16 + cI];
          sa[rt][ct][r] = sa[rt][ct][r] * scale + pv + mv;
        }
        float t = fmaxf(fmaxf(sa[rt][0][r], sa[rt][1][r]),
                        fmaxf(sa[rt][2][r], sa[rt][3][r]));
#pragma unroll
        for (int off = 1; off < 16; off <<= 1) t = fmaxf(t, __shfl_xor(t, off));
        float mn = fmaxf(mr[rt][r], t);
        float fsc = __expf(mr[rt][r] - mn);
        mr[rt][r] = mn;
        float sum = 0.f;
#pragma unroll
        for (int ct = 0; ct < 4; ct++) {
          float pp = __expf(sa[rt][ct][r] - mn);
          sa[rt][ct][r] = pp;
          sum += pp;
        }
#pragma unroll
        for (int off = 1; off < 16; off <<= 1) sum += __shfl_xor(sum, off);
        lr[rt][r] = lr[rt][r] * fsc + sum;
        o[rt][0][r] *= fsc;
        o[rt][1][r] *= fsc;
#pragma unroll
        for (int ct = 0; ct < 4; ct++)
          pw[(rt * 16 + gI * 4 + r) * 72 + ct * 16 + cI] = (bf16)sa[rt][ct][r];
      }
    }
    // this wave's P writes must land before re-reading as A-frags
    asm volatile("s_waitcnt lgkmcnt(0)" ::: "memory");
    __builtin_amdgcn_sched_barrier(0);
#pragma unroll
    for (int kc = 0; kc < 2; kc++) {
      bf16x8 pfr[2], vfr[2];
#pragma unroll
      for (int rt = 0; rt < 2; rt++)
        pfr[rt] = *(const bf16x8*)(pw + (rt * 16 + cI) * 72 + kc * 32 + gI * 8);
#pragma unroll
      for (int c2 = 0; c2 < 2; c2++)
        vfr[c2] = *(const bf16x8*)(vb + (c2 * 16 + cI) * 256 + kt * 64 + kc * 32 + gI * 8);
#pragma unroll
      for (int rt = 0; rt < 2; rt++) {
#pragma unroll
        for (int c2 = 0; c2 < 2; c2++)
          o[rt][c2] = MFMA(pfr[rt], vfr[c2], o[rt][c2]);
      }
    }
  }
#pragma unroll
  for (int rt = 0; rt < 2; rt++) {
#pragma unroll
    for (int c2 = 0; c2 < 2; c2++) {
#pragma unroll
      for (int r = 0; r < 4; r++) {
        int n = qrow0 + rt * 16 + gI * 4 + r;
        float val = o[rt][c2][r] / lr[rt][r];
        ctx[((size_t)(b << 8) + n) * 192 + h * 32 + c2 * 16 + cI] = (bf16)val;
      }
    }
  }
}

// ---------------------------------------------------------------------------
// Kernel D: out = ctx @ w_proj + b_proj, swapped orientation -> float4 stores.
// ---------------------------------------------------------------------------
#define SMEM_C (192 * 200 * 2)

__global__ __launch_bounds__(256) void proj_kernel(
    const bf16* __restrict__ ctx, const float* __restrict__ w_proj,
    const float* __restrict__ b_proj, float* __restrict__ out) {
  extern __shared__ char smem[];
  bf16* wt = (bf16*)smem;   // [192 c][200 k]
  int tid = threadIdx.x;
  for (int idx = tid; idx < 192 * 192; idx += 256) {
    int k = idx / 192, jj = idx % 192;
    wt[jj * 200 + k] = (bf16)w_proj[idx];
  }
  __syncthreads();
  const int lane = tid & 63, w = tid >> 6;
  const int cI = lane & 15, gI = lane >> 4;
  const int RB = blockIdx.x * 128;
  bf16x8 afr[2][6];
#pragma unroll
  for (int rt = 0; rt < 2; rt++) {
#pragma unroll
    for (int kk = 0; kk < 6; kk++)
      afr[rt][kk] = *(const bf16x8*)(ctx + (size_t)(RB + w * 32 + rt * 16 + cI) * 192 +
                                     kk * 32 + gI * 8);
  }
#pragma unroll
  for (int ct = 0; ct < 12; ct++) {
    bf16x8 wfr[6];
#pragma unroll
    for (int kk = 0; kk < 6; kk++)
      wfr[kk] = *(const bf16x8*)(wt + (ct * 16 + cI) * 200 + kk * 32 + gI * 8);
    f32x4 bv4 = *(const f32x4*)(b_proj + ct * 16 + gI * 4);
#pragma unroll
    for (int rt = 0; rt < 2; rt++) {
      f32x4 acc = {0.f, 0.f, 0.f, 0.f};
#pragma unroll
      for (int kk = 0; kk < 6; kk++) acc = MFMA(wfr[kk], afr[rt][kk], acc);
      f32x4 res;
#pragma unroll
      for (int r = 0; r < 4; r++) res[r] = acc[r] + bv4[r];
      int n = RB + w * 32 + rt * 16 + cI;
      *(f32x4*)(out + (size_t)n * 192 + ct * 16 + gI * 4) = res;
    }
  }
}

// ---------------------------------------------------------------------------
extern "C" void kernel_launch(void* const* d_in, const int* in_sizes, int n_in,
                              void* d_out, int out_size, void* d_ws, size_t ws_size,
                              hipStream_t stream) {
  (void)in_sizes; (void)n_in; (void)out_size; (void)ws_size;
  const float* x      = (const float*)d_in[0];
  const float* mask   = (const float*)d_in[1];
  const float* w_qkv  = (const float*)d_in[2];
  const float* b_qkv  = (const float*)d_in[3];
  const float* w_proj = (const float*)d_in[4];
  const float* b_proj = (const float*)d_in[5];
  const float* pw0    = (const float*)d_in[6];
  const float* pb0    = (const float*)d_in[7];
  const float* g1     = (const float*)d_in[8];
  const float* be1    = (const float*)d_in[9];
  const float* w1     = (const float*)d_in[10];
  const float* b1     = (const float*)d_in[11];
  const float* g2     = (const float*)d_in[12];
  const float* be2    = (const float*)d_in[13];
  const float* w2     = (const float*)d_in[14];
  const float* b2     = (const float*)d_in[15];
  const float* g3     = (const float*)d_in[16];
  const float* be3    = (const float*)d_in[17];
  const float* w3     = (const float*)d_in[18];
  const float* b3     = (const float*)d_in[19];

  // ws layout (peak 100,687,872 B — within prior rounds' footprint):
  //   posw @ 0          (24576)
  //   qw   @ 24576      (25165824)  bf16 [b][h][n][32]
  //   kw   @ 25190400   (25165824)
  //   vwT  @ 50356224   (25165824)  bf16 [b][h][32][n]
  //   ctx  @ 75522048   (25165824)  -- wqT (221184) aliases here, dead after qkv
  char* ws = (char*)d_ws;
  float* posw = (float*)ws;
  bf16*  qw   = (bf16*)(ws + 24576);
  bf16*  kw   = (bf16*)(ws + 25190400);
  bf16*  vwT  = (bf16*)(ws + 50356224);
  bf16*  ctx  = (bf16*)(ws + 75522048);
  bf16*  wqT  = (bf16*)(ws + 75522048);   // alias: lifetime precast -> qkv only
  float* outp = (float*)d_out;

  hipFuncSetAttribute((const void*)proj_kernel,
                      hipFuncAttributeMaxDynamicSharedMemorySize, SMEM_C);

  precast_kernel<<<dim3(432), dim3(256), 0, stream>>>(w_qkv, wqT);
  pos_mlp_kernel<<<dim3(4), dim3(256), 0, stream>>>(
      pw0, pb0, g1, be1, w1, b1, g2, be2, w2, b2, g3, be3, w3, b3, posw);
  qkv_gemm_kernel<<<dim3(512), dim3(256), 0, stream>>>(
      x, wqT, b_qkv, qw, kw, vwT);
  attn_kernel<<<dim3(3072), dim3(256), SMEM_A, stream>>>(
      qw, kw, vwT, mask, posw, ctx);
  proj_kernel<<<dim3(512), dim3(256), SMEM_C, stream>>>(
      ctx, w_proj, b_proj, outp);
}